// Round 4
// baseline (336.832 us; speedup 1.0000x reference)
//
#include <hip/hip_runtime.h>

typedef unsigned short u16;
typedef __attribute__((ext_vector_type(8))) short bf16x8;
typedef __attribute__((ext_vector_type(4))) float f32x4;

#define LOG2E 1.4426950408889634f
#define QSCALE (LOG2E / 8.0f)   // fold 1/sqrt(64) and ln->log2 into Q projection
#define PSTR 136                // attn P-tile row stride: 68 words ≡ 4 mod 32 -> conflict-minimal

__device__ __forceinline__ u16 f2bf(float f) {
  union { float f; unsigned u; } v; v.f = f;
  unsigned r = v.u + 0x7fffu + ((v.u >> 16) & 1u);   // RNE
  return (u16)(r >> 16);
}

// async global->LDS, 16B per lane. LDS dest must be wave-uniform base + lane*16.
__device__ __forceinline__ void gload_lds16(const void* g, void* l) {
  __builtin_amdgcn_global_load_lds(
      (const __attribute__((address_space(1))) unsigned int*)(unsigned long long)g,
      (__attribute__((address_space(3))) unsigned int*)(unsigned int)(unsigned long long)l,
      16, 0, 0);
}

// ---------------- fused prep: 7x f32->bf16 convert + mask bit-pack ----------------
__global__ __launch_bounds__(256) void prep_kernel(
    const float* __restrict__ q, const float* __restrict__ k, const float* __restrict__ v,
    const float* __restrict__ wq, const float* __restrict__ wk, const float* __restrict__ wv,
    const float* __restrict__ wo, const int* __restrict__ mask,
    u16* __restrict__ Xq, u16* __restrict__ Xk, u16* __restrict__ Xv,
    u16* __restrict__ Wq, u16* __restrict__ Wk, u16* __restrict__ Wv, u16* __restrict__ Wo,
    unsigned long long* __restrict__ Mp) {
  const int bx = blockIdx.x;
  if (bx < 16384) {
    const float* src; u16* dst; float sc; int idx;
    if (bx < 12288) {
      int seg = bx >> 12;
      idx = (bx & 4095) * 256 + threadIdx.x;
      src = seg == 0 ? q : (seg == 1 ? k : v);
      dst = seg == 0 ? Xq : (seg == 1 ? Xk : Xv);
      sc = 1.f;
    } else {
      int t = bx - 12288, seg = t >> 10;
      idx = (t & 1023) * 256 + threadIdx.x;
      src = seg == 0 ? wq : (seg == 1 ? wk : (seg == 2 ? wv : wo));
      dst = seg == 0 ? Wq : (seg == 1 ? Wk : (seg == 2 ? Wv : Wo));
      sc = seg == 0 ? QSCALE : 1.f;
    }
    float4 x = ((const float4*)src)[idx];
    ushort4 o;
    o.x = f2bf(x.x * sc); o.y = f2bf(x.y * sc);
    o.z = f2bf(x.z * sc); o.w = f2bf(x.w * sc);
    ((ushort4*)dst)[idx] = o;
  } else {
    int gw = (((bx - 16384) * 256) + threadIdx.x) >> 6;   // [0,16384)
    int lane = threadIdx.x & 63;
    for (int w = gw; w < 131072; w += 16384) {
      int m = mask[(size_t)w * 64 + lane];
      unsigned long long b = __ballot(m != 0);
      if (lane == 0) Mp[w] = b;
    }
  }
}

// ---------------- fused GEMM: D[m][n] = sum_k A[m][k]*B[n][k]  (both k-contig, lda=ldb=1024)
// mode 0: A=Wq(f) B=Xq(s) -> Qd[b,h,s,d] bf16 (+bq*QSCALE)
// mode 1: A=Wk    B=Xk    -> Kd[b,h,s,d] bf16 (+bk)
// mode 2: A=Xv(s) B=Wv(f) -> Vtd[b,h,d,s] bf16 (+bv)
// mode 3: A=Wo(f) B=ctx(s)-> outp[s][f] f32 (raw matmul; bias+resid fused in LN)
// launch_bounds (256,3): 3 blocks/CU so the 768-block QKV launch is fully co-resident.
__global__ __launch_bounds__(256, 3) void gemm_kernel(
    const u16* __restrict__ Xq, const u16* __restrict__ Xk, const u16* __restrict__ Xv,
    const u16* __restrict__ Wq, const u16* __restrict__ Wk, const u16* __restrict__ Wv,
    const u16* __restrict__ Wo, const u16* __restrict__ Ctx,
    const float* __restrict__ bq, const float* __restrict__ bk, const float* __restrict__ bv,
    u16* __restrict__ Qd, u16* __restrict__ Kd, u16* __restrict__ Vtd, float* __restrict__ outp,
    int mode_base) {
  __shared__ __align__(16) u16 SH[17408];  // main loop: As[4096]+Bs[4096]; epilogue: 34KB transpose tile
  u16* As = SH;
  u16* Bs = SH + 4096;
  const int mode = mode_base + blockIdx.z;
  const int tid = threadIdx.x;
  const int wid = tid >> 6, l = tid & 63, quad = l >> 4, ln = l & 15;
  const int wm = wid >> 1, wn = wid & 1;

  const u16 *A, *B; const float* bias;
  if (mode == 0)      { A = Wq; B = Xq;  bias = bq; }
  else if (mode == 1) { A = Wk; B = Xk;  bias = bk; }
  else if (mode == 2) { A = Xv; B = Wv;  bias = bv; }
  else                { A = Wo; B = Ctx; bias = bq; }
  int mBase, nBase;
  if (mode == 2) { mBase = blockIdx.x * 128; nBase = blockIdx.y * 128; }
  else           { mBase = blockIdx.y * 128; nBase = blockIdx.x * 128; }

  const u16* Ag = A + (size_t)mBase * 1024;
  const u16* Bg = B + (size_t)nBase * 1024;

  f32x4 acc[4][4] = {};

  for (int k0 = 0; k0 < 1024; k0 += 32) {
    if (k0) __syncthreads();
    {
      int i0 = tid, i1 = tid + 256;
      gload_lds16(Ag + (size_t)(i0 & 127) * 1024 + k0 + (i0 >> 7) * 8, &As[i0 * 8]);
      gload_lds16(Ag + (size_t)(i1 & 127) * 1024 + k0 + (i1 >> 7) * 8, &As[i1 * 8]);
      gload_lds16(Bg + (size_t)(i0 & 127) * 1024 + k0 + (i0 >> 7) * 8, &Bs[i0 * 8]);
      gload_lds16(Bg + (size_t)(i1 & 127) * 1024 + k0 + (i1 >> 7) * 8, &Bs[i1 * 8]);
    }
    __syncthreads();
    bf16x8 af[4], bf[4];
#pragma unroll
    for (int i = 0; i < 4; ++i)
      af[i] = *(const bf16x8*)&As[(quad * 128 + wm * 64 + i * 16 + ln) * 8];
#pragma unroll
    for (int j = 0; j < 4; ++j)
      bf[j] = *(const bf16x8*)&Bs[(quad * 128 + wn * 64 + j * 16 + ln) * 8];
#pragma unroll
    for (int i = 0; i < 4; ++i)
#pragma unroll
      for (int j = 0; j < 4; ++j)
        acc[i][j] = __builtin_amdgcn_mfma_f32_16x16x32_bf16(af[i], bf[j], acc[i][j], 0, 0, 0);
  }

  __syncthreads();  // all waves done with As/Bs before reusing SH for the transpose

  if (mode <= 1) {
    // acc(i,j): m=f (4 contig per thread), n=s. Stage SH as [s 128][f stride 136].
    const float bscale = (mode == 0) ? QSCALE : 1.0f;
#pragma unroll
    for (int i = 0; i < 4; ++i) {
      int f0 = wm * 64 + i * 16 + quad * 4;
      float4 bb = *(const float4*)(bias + mBase + f0);
#pragma unroll
      for (int j = 0; j < 4; ++j) {
        int sl = wn * 64 + j * 16 + ln;
        f32x4 v = acc[i][j];
        ushort4 o;
        o.x = f2bf(v[0] + bb.x * bscale); o.y = f2bf(v[1] + bb.y * bscale);
        o.z = f2bf(v[2] + bb.z * bscale); o.w = f2bf(v[3] + bb.w * bscale);
        *(ushort4*)&SH[sl * 136 + f0] = o;
      }
    }
    __syncthreads();
    u16* dstQK = (mode == 0) ? Qd : Kd;
#pragma unroll
    for (int p = 0; p < 8; ++p) {
      int sl = p * 16 + (tid >> 4);
      int fl = (tid & 15) * 8;
      uint4 w = *(const uint4*)&SH[sl * 136 + fl];
      int s = nBase + sl, f = mBase + fl;
      int h = f >> 6, d = f & 63, b = s >> 11, sr = s & 2047;
      *(uint4*)(dstQK + (((size_t)(b * 16 + h) * 2048 + sr) * 64 + d)) = w;
    }
  } else if (mode == 2) {
    // acc(i,j): m=s (4 contig per thread), n=f. Stage SH as [f 128][s stride 136].
#pragma unroll
    for (int j = 0; j < 4; ++j) {
      int fl = wn * 64 + j * 16 + ln;
      float bb = bias[nBase + fl];
#pragma unroll
      for (int i = 0; i < 4; ++i) {
        int s0 = wm * 64 + i * 16 + quad * 4;
        f32x4 v = acc[i][j];
        ushort4 o;
        o.x = f2bf(v[0] + bb); o.y = f2bf(v[1] + bb);
        o.z = f2bf(v[2] + bb); o.w = f2bf(v[3] + bb);
        *(ushort4*)&SH[fl * 136 + s0] = o;
      }
    }
    __syncthreads();
#pragma unroll
    for (int p = 0; p < 8; ++p) {
      int fl = p * 16 + (tid >> 4);
      int sl = (tid & 15) * 8;
      uint4 w = *(const uint4*)&SH[fl * 136 + sl];
      int f = nBase + fl, s = mBase + sl;
      int h = f >> 6, d = f & 63, b = s >> 11, sr = s & 2047;
      *(uint4*)(Vtd + (((size_t)(b * 16 + h) * 64 + d) * 2048 + sr)) = w;
    }
  } else {
    // mode 3, f32 out [s][1024 f]. Two n-halves (wn==h2 owns s_local in [h2*64, h2*64+64)).
    float* ES = (float*)SH;  // [64][stride 132] f32
#pragma unroll
    for (int h2 = 0; h2 < 2; ++h2) {
      if (h2) __syncthreads();
      if (wn == h2) {
#pragma unroll
        for (int i = 0; i < 4; ++i) {
          int f0 = wm * 64 + i * 16 + quad * 4;
#pragma unroll
          for (int j = 0; j < 4; ++j) {
            int sl = j * 16 + ln;
            f32x4 v = acc[i][j];
            float4 o; o.x = v[0]; o.y = v[1]; o.z = v[2]; o.w = v[3];
            *(float4*)&ES[sl * 132 + f0] = o;
          }
        }
      }
      __syncthreads();
#pragma unroll
      for (int p = 0; p < 8; ++p) {
        int sl = p * 8 + (tid >> 5);
        int fl = (tid & 31) * 4;
        float4 w = *(const float4*)&ES[sl * 132 + fl];
        int s = nBase + h2 * 64 + sl;
        *(float4*)(outp + (size_t)s * 1024 + mBase + fl) = w;
      }
    }
  }
}

// ---------------- flash attention (no-max exp2 softmax), 64-row q tiles ----------------
// grid (SQ/64, B*H) = (32,32) = 1024 blocks -> 4 blocks/CU co-resident.
// Each wave owns one 16-q tile. S^T = K.Q^T per 128-kv tile; P = exp2(s_masked);
// l = P.1 via ones-column MFMA (lands in oacc register layout).
__global__ __launch_bounds__(256, 4) void attn_kernel(
    const u16* __restrict__ Qg, const u16* __restrict__ Kg, const u16* __restrict__ Vtg,
    const unsigned* __restrict__ Mp, u16* __restrict__ ctx) {
  __shared__ __align__(16) u16 UN[8704];  // union: Ks[8][128][8](16KB) / Ps[64][PSTR](17KB) / Os[64][64]
  __shared__ __align__(16) u16 Vs[8192];  // [kvg 16][d 64][8]
  const int tid = threadIdx.x;
  const int wid = tid >> 6, l = tid & 63, quad = l >> 4, ln = l & 15;
  const int q4 = quad * 4;
  const int bh = blockIdx.y, b = bh >> 4, h = bh & 15;
  const int qBase = blockIdx.x * 64;
  const int wq = wid * 16;

  bf16x8 qf[2];  // B-operand fragments of Q (n=q=ln row, k=d contiguous)
#pragma unroll
  for (int kc = 0; kc < 2; ++kc)
    qf[kc] = *(const bf16x8*)(Qg + (((size_t)bh * 2048 + qBase + wq + ln) * 64 +
                                    kc * 32 + quad * 8));

  f32x4 oacc[4] = {};
  f32x4 lsum = {};
  const bf16x8 vone = {(short)0x3F80, (short)0x3F80, (short)0x3F80, (short)0x3F80,
                       (short)0x3F80, (short)0x3F80, (short)0x3F80, (short)0x3F80};

  const unsigned* mrow = Mp + ((size_t)b * 2048 + qBase + wq + ln) * 64;  // 64 u32 per q row

  for (int it = 0; it < 16; ++it) {
    const int kvB = it * 128;
    __syncthreads();  // prev-iter PV reads of Ps/Vs complete
#pragma unroll
    for (int r = 0; r < 4; ++r) {
      int c = r * 256 + tid;
      gload_lds16(Kg + (((size_t)bh * 2048 + kvB + (c & 127)) * 64 + (c >> 7) * 8), &UN[c * 8]);
    }
#pragma unroll
    for (int r = 0; r < 4; ++r) {
      int c = r * 256 + tid;
      gload_lds16(Vtg + (((size_t)bh * 64 + (c & 63)) * 2048 + kvB + (c >> 6) * 8), &Vs[c * 8]);
    }
    __syncthreads();  // staging visible

    f32x4 s[8];
#pragma unroll
    for (int mt = 0; mt < 8; ++mt) {
      bf16x8 k0 = *(const bf16x8*)&UN[((0 + quad) * 128 + mt * 16 + ln) * 8];
      bf16x8 k1 = *(const bf16x8*)&UN[((4 + quad) * 128 + mt * 16 + ln) * 8];
      f32x4 z = {0.f, 0.f, 0.f, 0.f};
      z = __builtin_amdgcn_mfma_f32_16x16x32_bf16(k0, qf[0], z, 0, 0, 0);
      s[mt] = __builtin_amdgcn_mfma_f32_16x16x32_bf16(k1, qf[1], z, 0, 0, 0);
    }

    unsigned ww[4];
    {
      uint4 m0 = *(const uint4*)(mrow + it * 4);
      ww[0] = m0.x; ww[1] = m0.y; ww[2] = m0.z; ww[3] = m0.w;
    }
    uint2 pk[8];
#pragma unroll
    for (int mt = 0; mt < 8; ++mt) {
      unsigned nib = (ww[mt >> 1] >> ((mt & 1) * 16 + q4)) & 0xFu;
      float p0 = __builtin_amdgcn_exp2f((nib & 1u) ? s[mt][0] : -1e30f);
      float p1 = __builtin_amdgcn_exp2f((nib & 2u) ? s[mt][1] : -1e30f);
      float p2 = __builtin_amdgcn_exp2f((nib & 4u) ? s[mt][2] : -1e30f);
      float p3 = __builtin_amdgcn_exp2f((nib & 8u) ? s[mt][3] : -1e30f);
      pk[mt].x = __builtin_amdgcn_perm(__float_as_uint(p1) + 0x8000u,
                                       __float_as_uint(p0) + 0x8000u, 0x07060302u);
      pk[mt].y = __builtin_amdgcn_perm(__float_as_uint(p3) + 0x8000u,
                                       __float_as_uint(p2) + 0x8000u, 0x07060302u);
    }

    __syncthreads();  // all waves finished reading Ks (UN) -> safe to overwrite with Ps
    {
      int qrow = wq + ln;
#pragma unroll
      for (int mt = 0; mt < 8; ++mt)
        *(uint2*)&UN[qrow * PSTR + mt * 16 + q4] = pk[mt];
    }
    __syncthreads();  // Ps visible

#pragma unroll
    for (int kc2 = 0; kc2 < 4; ++kc2) {
      bf16x8 aP = *(const bf16x8*)&UN[(wq + ln) * PSTR + kc2 * 32 + quad * 8];
#pragma unroll
      for (int nt = 0; nt < 4; ++nt) {
        bf16x8 bV = *(const bf16x8*)&Vs[((kc2 * 4 + quad) * 64 + nt * 16 + ln) * 8];
        oacc[nt] = __builtin_amdgcn_mfma_f32_16x16x32_bf16(aP, bV, oacc[nt], 0, 0, 0);
      }
      lsum = __builtin_amdgcn_mfma_f32_16x16x32_bf16(aP, vone, lsum, 0, 0, 0);
    }
  }

  __syncthreads();  // last PV reads done before Os overwrites UN
#pragma unroll
  for (int r = 0; r < 4; ++r) {
    float il = 1.0f / lsum[r];
    int q = wq + q4 + r;
#pragma unroll
    for (int nt = 0; nt < 4; ++nt)
      UN[q * 64 + nt * 16 + ln] = f2bf(oacc[nt][r] * il);
  }
  __syncthreads();
#pragma unroll
  for (int r = 0; r < 2; ++r) {
    int c = r * 256 + tid;
    int q = c >> 3, ch = c & 7;
    *(uint4*)(ctx + ((size_t)(b * 2048 + qBase + q) * 1024 + h * 64 + ch * 8)) =
        *(const uint4*)&UN[q * 64 + ch * 8];
  }
}

// ---------------- LayerNorm (fused +bo +residual) over 1024 features ----------------
__global__ __launch_bounds__(256) void ln_kernel(const float* __restrict__ x,
                                                 const float* __restrict__ resid,
                                                 const float* __restrict__ bo,
                                                 const float* __restrict__ gamma,
                                                 const float* __restrict__ beta,
                                                 float* __restrict__ out) {
  __shared__ float red[8];
  const int tid = threadIdx.x;
  const size_t row = blockIdx.x;
  float4 v = ((const float4*)(x + row * 1024))[tid];
  const float4 rr = ((const float4*)(resid + row * 1024))[tid];
  const float4 bb = ((const float4*)bo)[tid];
  v.x += rr.x + bb.x; v.y += rr.y + bb.y; v.z += rr.z + bb.z; v.w += rr.w + bb.w;
  float s1 = v.x + v.y + v.z + v.w;
  float s2 = v.x * v.x + v.y * v.y + v.z * v.z + v.w * v.w;
#pragma unroll
  for (int o = 32; o >= 1; o >>= 1) {
    s1 += __shfl_xor(s1, o);
    s2 += __shfl_xor(s2, o);
  }
  if ((tid & 63) == 0) { red[(tid >> 6) * 2] = s1; red[(tid >> 6) * 2 + 1] = s2; }
  __syncthreads();
  s1 = red[0] + red[2] + red[4] + red[6];
  s2 = red[1] + red[3] + red[5] + red[7];
  float mu = s1 * (1.f / 1024.f);
  float var = s2 * (1.f / 1024.f) - mu * mu;
  float inv = rsqrtf(var + 1e-5f);
  float4 g = ((const float4*)gamma)[tid];
  float4 be = ((const float4*)beta)[tid];
  float4 o;
  o.x = (v.x - mu) * inv * g.x + be.x;
  o.y = (v.y - mu) * inv * g.y + be.y;
  o.z = (v.z - mu) * inv * g.z + be.z;
  o.w = (v.w - mu) * inv * g.w + be.w;
  ((float4*)(out + row * 1024))[tid] = o;
}

extern "C" void kernel_launch(void* const* d_in, const int* in_sizes, int n_in,
                              void* d_out, int out_size, void* d_ws, size_t ws_size,
                              hipStream_t stream) {
  const float* query = (const float*)d_in[0];
  const float* key   = (const float*)d_in[1];
  const float* value = (const float*)d_in[2];
  const int*   mask  = (const int*)d_in[3];
  const float* w_q = (const float*)d_in[4];
  const float* b_q = (const float*)d_in[5];
  const float* w_k = (const float*)d_in[6];
  const float* b_k = (const float*)d_in[7];
  const float* w_v = (const float*)d_in[8];
  const float* b_v = (const float*)d_in[9];
  const float* w_o = (const float*)d_in[10];
  const float* b_o = (const float*)d_in[11];
  const float* ln_g = (const float*)d_in[12];
  const float* ln_b = (const float*)d_in[13];
  float* out = (float*)d_out;

  char* ws = (char*)d_ws;
  u16* Xq = (u16*)(ws + ((size_t)0 << 20));   // 8MB, reused as ctx after QKV GEMM
  u16* Xk = (u16*)(ws + ((size_t)8 << 20));   // 8MB  } reused as outpre (16MB f32)
  u16* Xv = (u16*)(ws + ((size_t)16 << 20));  // 8MB  }
  float* outpre = (float*)(ws + ((size_t)8 << 20));
  u16* Wq = (u16*)(ws + ((size_t)24 << 20));
  u16* Wk = (u16*)(ws + ((size_t)26 << 20));
  u16* Wv = (u16*)(ws + ((size_t)28 << 20));
  u16* Wo = (u16*)(ws + ((size_t)30 << 20));
  u16* Qd = (u16*)(ws + ((size_t)32 << 20));   // [b,h,s,64] bf16
  u16* Kd = (u16*)(ws + ((size_t)40 << 20));   // [b,h,s,64]
  u16* Vtd = (u16*)(ws + ((size_t)48 << 20));  // [b,h,64,s]
  unsigned long long* Mp = (unsigned long long*)(ws + ((size_t)56 << 20));  // 1MB
  u16* ctx = Xq;

  prep_kernel<<<20480, 256, 0, stream>>>(query, key, value, w_q, w_k, w_v, w_o, mask,
                                         Xq, Xk, Xv, Wq, Wk, Wv, Wo, Mp);
  gemm_kernel<<<dim3(32, 8, 3), 256, 0, stream>>>(Xq, Xk, Xv, Wq, Wk, Wv, Wo, ctx,
      b_q, b_k, b_v, Qd, Kd, Vtd, outpre, 0);
  attn_kernel<<<dim3(32, 32), 256, 0, stream>>>(Qd, Kd, Vtd, (const unsigned*)Mp, ctx);
  gemm_kernel<<<dim3(32, 8, 1), 256, 0, stream>>>(Xq, Xk, Xv, Wq, Wk, Wv, Wo, ctx,
      b_q, b_k, b_v, Qd, Kd, Vtd, outpre, 3);
  ln_kernel<<<4096, 256, 0, stream>>>(outpre, query, b_o, ln_g, ln_b, out);
}

// Round 5
// 317.174 us; speedup vs baseline: 1.0620x; 1.0620x over previous
//
#include <hip/hip_runtime.h>

typedef unsigned short u16;
typedef __attribute__((ext_vector_type(8))) short bf16x8;
typedef __attribute__((ext_vector_type(4))) float f32x4;

#define LOG2E 1.4426950408889634f
#define QSCALE (LOG2E / 8.0f)   // fold 1/sqrt(64) and ln->log2 into Q projection
#define PSTR 136                // attn P-tile row stride (measured best: R2's 144 doubled conflicts)

__device__ __forceinline__ u16 f2bf(float f) {
  union { float f; unsigned u; } v; v.f = f;
  unsigned r = v.u + 0x7fffu + ((v.u >> 16) & 1u);   // RNE
  return (u16)(r >> 16);
}

// async global->LDS, 16B per lane. LDS dest must be wave-uniform base + lane*16.
__device__ __forceinline__ void gload_lds16(const void* g, void* l) {
  __builtin_amdgcn_global_load_lds(
      (const __attribute__((address_space(1))) unsigned int*)(unsigned long long)g,
      (__attribute__((address_space(3))) unsigned int*)(unsigned int)(unsigned long long)l,
      16, 0, 0);
}

// ---------------- fused prep: 7x f32->bf16 convert + mask bit-pack ----------------
__global__ __launch_bounds__(256) void prep_kernel(
    const float* __restrict__ q, const float* __restrict__ k, const float* __restrict__ v,
    const float* __restrict__ wq, const float* __restrict__ wk, const float* __restrict__ wv,
    const float* __restrict__ wo, const int* __restrict__ mask,
    u16* __restrict__ Xq, u16* __restrict__ Xk, u16* __restrict__ Xv,
    u16* __restrict__ Wq, u16* __restrict__ Wk, u16* __restrict__ Wv, u16* __restrict__ Wo,
    unsigned long long* __restrict__ Mp) {
  const int bx = blockIdx.x;
  if (bx < 16384) {
    const float* src; u16* dst; float sc; int idx;
    if (bx < 12288) {
      int seg = bx >> 12;
      idx = (bx & 4095) * 256 + threadIdx.x;
      src = seg == 0 ? q : (seg == 1 ? k : v);
      dst = seg == 0 ? Xq : (seg == 1 ? Xk : Xv);
      sc = 1.f;
    } else {
      int t = bx - 12288, seg = t >> 10;
      idx = (t & 1023) * 256 + threadIdx.x;
      src = seg == 0 ? wq : (seg == 1 ? wk : (seg == 2 ? wv : wo));
      dst = seg == 0 ? Wq : (seg == 1 ? Wk : (seg == 2 ? Wv : Wo));
      sc = seg == 0 ? QSCALE : 1.f;
    }
    float4 x = ((const float4*)src)[idx];
    ushort4 o;
    o.x = f2bf(x.x * sc); o.y = f2bf(x.y * sc);
    o.z = f2bf(x.z * sc); o.w = f2bf(x.w * sc);
    ((ushort4*)dst)[idx] = o;
  } else {
    int gw = (((bx - 16384) * 256) + threadIdx.x) >> 6;   // [0,16384)
    int lane = threadIdx.x & 63;
    for (int w = gw; w < 131072; w += 16384) {
      int m = mask[(size_t)w * 64 + lane];
      unsigned long long b = __ballot(m != 0);
      if (lane == 0) Mp[w] = b;
    }
  }
}

// ---------------- fused GEMM: D[m][n] = sum_k A[m][k]*B[n][k]  (both k-contig, lda=ldb=1024)
// mode 0: A=Wq(f) B=Xq(s) -> Qd[b,h,s,d] bf16 (+bq*QSCALE)
// mode 1: A=Wk    B=Xk    -> Kd[b,h,s,d] bf16 (+bk)
// mode 2: A=Xv(s) B=Wv(f) -> Vtd[b,h,d,s] bf16 (+bv)
// mode 3: A=Wo(f) B=ctx(s)-> outp[s][f] f32 (raw matmul; bias+resid fused in LN)
__global__ __launch_bounds__(256, 3) void gemm_kernel(
    const u16* __restrict__ Xq, const u16* __restrict__ Xk, const u16* __restrict__ Xv,
    const u16* __restrict__ Wq, const u16* __restrict__ Wk, const u16* __restrict__ Wv,
    const u16* __restrict__ Wo, const u16* __restrict__ Ctx,
    const float* __restrict__ bq, const float* __restrict__ bk, const float* __restrict__ bv,
    u16* __restrict__ Qd, u16* __restrict__ Kd, u16* __restrict__ Vtd, float* __restrict__ outp,
    int mode_base) {
  __shared__ __align__(16) u16 SH[17408];  // main loop: As[4096]+Bs[4096]; epilogue: 34KB transpose tile
  u16* As = SH;
  u16* Bs = SH + 4096;
  const int mode = mode_base + blockIdx.z;
  const int tid = threadIdx.x;
  const int wid = tid >> 6, l = tid & 63, quad = l >> 4, ln = l & 15;
  const int wm = wid >> 1, wn = wid & 1;

  const u16 *A, *B; const float* bias;
  if (mode == 0)      { A = Wq; B = Xq;  bias = bq; }
  else if (mode == 1) { A = Wk; B = Xk;  bias = bk; }
  else if (mode == 2) { A = Xv; B = Wv;  bias = bv; }
  else                { A = Wo; B = Ctx; bias = bq; }
  int mBase, nBase;
  if (mode == 2) { mBase = blockIdx.x * 128; nBase = blockIdx.y * 128; }
  else           { mBase = blockIdx.y * 128; nBase = blockIdx.x * 128; }

  const u16* Ag = A + (size_t)mBase * 1024;
  const u16* Bg = B + (size_t)nBase * 1024;

  f32x4 acc[4][4] = {};

  for (int k0 = 0; k0 < 1024; k0 += 32) {
    if (k0) __syncthreads();
    {
      int i0 = tid, i1 = tid + 256;
      gload_lds16(Ag + (size_t)(i0 & 127) * 1024 + k0 + (i0 >> 7) * 8, &As[i0 * 8]);
      gload_lds16(Ag + (size_t)(i1 & 127) * 1024 + k0 + (i1 >> 7) * 8, &As[i1 * 8]);
      gload_lds16(Bg + (size_t)(i0 & 127) * 1024 + k0 + (i0 >> 7) * 8, &Bs[i0 * 8]);
      gload_lds16(Bg + (size_t)(i1 & 127) * 1024 + k0 + (i1 >> 7) * 8, &Bs[i1 * 8]);
    }
    __syncthreads();
    bf16x8 af[4], bf[4];
#pragma unroll
    for (int i = 0; i < 4; ++i)
      af[i] = *(const bf16x8*)&As[(quad * 128 + wm * 64 + i * 16 + ln) * 8];
#pragma unroll
    for (int j = 0; j < 4; ++j)
      bf[j] = *(const bf16x8*)&Bs[(quad * 128 + wn * 64 + j * 16 + ln) * 8];
#pragma unroll
    for (int i = 0; i < 4; ++i)
#pragma unroll
      for (int j = 0; j < 4; ++j)
        acc[i][j] = __builtin_amdgcn_mfma_f32_16x16x32_bf16(af[i], bf[j], acc[i][j], 0, 0, 0);
  }

  __syncthreads();  // all waves done with As/Bs before reusing SH for the transpose

  if (mode <= 1) {
    const float bscale = (mode == 0) ? QSCALE : 1.0f;
#pragma unroll
    for (int i = 0; i < 4; ++i) {
      int f0 = wm * 64 + i * 16 + quad * 4;
      float4 bb = *(const float4*)(bias + mBase + f0);
#pragma unroll
      for (int j = 0; j < 4; ++j) {
        int sl = wn * 64 + j * 16 + ln;
        f32x4 v = acc[i][j];
        ushort4 o;
        o.x = f2bf(v[0] + bb.x * bscale); o.y = f2bf(v[1] + bb.y * bscale);
        o.z = f2bf(v[2] + bb.z * bscale); o.w = f2bf(v[3] + bb.w * bscale);
        *(ushort4*)&SH[sl * 136 + f0] = o;
      }
    }
    __syncthreads();
    u16* dstQK = (mode == 0) ? Qd : Kd;
#pragma unroll
    for (int p = 0; p < 8; ++p) {
      int sl = p * 16 + (tid >> 4);
      int fl = (tid & 15) * 8;
      uint4 w = *(const uint4*)&SH[sl * 136 + fl];
      int s = nBase + sl, f = mBase + fl;
      int h = f >> 6, d = f & 63, b = s >> 11, sr = s & 2047;
      *(uint4*)(dstQK + (((size_t)(b * 16 + h) * 2048 + sr) * 64 + d)) = w;
    }
  } else if (mode == 2) {
#pragma unroll
    for (int j = 0; j < 4; ++j) {
      int fl = wn * 64 + j * 16 + ln;
      float bb = bias[nBase + fl];
#pragma unroll
      for (int i = 0; i < 4; ++i) {
        int s0 = wm * 64 + i * 16 + quad * 4;
        f32x4 v = acc[i][j];
        ushort4 o;
        o.x = f2bf(v[0] + bb); o.y = f2bf(v[1] + bb);
        o.z = f2bf(v[2] + bb); o.w = f2bf(v[3] + bb);
        *(ushort4*)&SH[fl * 136 + s0] = o;
      }
    }
    __syncthreads();
#pragma unroll
    for (int p = 0; p < 8; ++p) {
      int fl = p * 16 + (tid >> 4);
      int sl = (tid & 15) * 8;
      uint4 w = *(const uint4*)&SH[fl * 136 + sl];
      int f = nBase + fl, s = mBase + sl;
      int h = f >> 6, d = f & 63, b = s >> 11, sr = s & 2047;
      *(uint4*)(Vtd + (((size_t)(b * 16 + h) * 64 + d) * 2048 + sr)) = w;
    }
  } else {
    float* ES = (float*)SH;  // [64][stride 132] f32
#pragma unroll
    for (int h2 = 0; h2 < 2; ++h2) {
      if (h2) __syncthreads();
      if (wn == h2) {
#pragma unroll
        for (int i = 0; i < 4; ++i) {
          int f0 = wm * 64 + i * 16 + quad * 4;
#pragma unroll
          for (int j = 0; j < 4; ++j) {
            int sl = j * 16 + ln;
            f32x4 v = acc[i][j];
            float4 o; o.x = v[0]; o.y = v[1]; o.z = v[2]; o.w = v[3];
            *(float4*)&ES[sl * 132 + f0] = o;
          }
        }
      }
      __syncthreads();
#pragma unroll
      for (int p = 0; p < 8; ++p) {
        int sl = p * 8 + (tid >> 5);
        int fl = (tid & 31) * 4;
        float4 w = *(const float4*)&ES[sl * 132 + fl];
        int s = nBase + h2 * 64 + sl;
        *(float4*)(outp + (size_t)s * 1024 + mBase + fl) = w;
      }
    }
  }
}

// ---------------- flash attention (no-max exp2 softmax), 128-q tiles, XCD-swizzled ----------------
// 1-D grid of 512 blocks. bh = (L&7)+8*(L>>7), qtile = (L>>3)&15: all 16 blocks sharing one
// head's K/V map to the same XCD (id = const mod 8) -> K/V stays L2-resident (4 heads x 512KB
// = 2MB per XCD). P has its own LDS region; each wave writes/reads only its own 32-row P band,
// so P write->PV read needs no barrier -> 2 barriers/iter (was 4).
__global__ __launch_bounds__(256, 2) void attn_kernel(
    const u16* __restrict__ Qg, const u16* __restrict__ Kg, const u16* __restrict__ Vtg,
    const unsigned* __restrict__ Mp, u16* __restrict__ ctx) {
  __shared__ __align__(16) u16 Ks[8192];   // [dg 8][kv 128][8]
  __shared__ __align__(16) u16 Vs[8192];   // [kvg 16][d 64][8]
  __shared__ __align__(16) u16 Ps[17408];  // [q 128][PSTR]; reused as Os[128][64] in epilogue
  const int tid = threadIdx.x;
  const int wid = tid >> 6, l = tid & 63, quad = l >> 4, ln = l & 15;
  const int q4 = quad * 4;
  const int L = blockIdx.x;
  const int bh = (L & 7) + 8 * (L >> 7);
  const int b = bh >> 4, h = bh & 15;
  const int qBase = ((L >> 3) & 15) * 128;
  const int wq = wid * 32;

  bf16x8 qf[2][2];  // B-operand fragments of Q (n=q=ln row, k=d contiguous)
#pragma unroll
  for (int qt = 0; qt < 2; ++qt)
#pragma unroll
    for (int kc = 0; kc < 2; ++kc)
      qf[qt][kc] = *(const bf16x8*)(Qg + (((size_t)bh * 2048 + qBase + wq + qt * 16 + ln) * 64 +
                                          kc * 32 + quad * 8));

  f32x4 oacc[2][4] = {};
  f32x4 lsum[2] = {};
  const bf16x8 vone = {(short)0x3F80, (short)0x3F80, (short)0x3F80, (short)0x3F80,
                       (short)0x3F80, (short)0x3F80, (short)0x3F80, (short)0x3F80};

  const unsigned* mrow[2];  // 64 u32 mask words per q row
  mrow[0] = Mp + ((size_t)b * 2048 + qBase + wq + ln) * 64;
  mrow[1] = mrow[0] + 16 * 64;

  for (int it = 0; it < 16; ++it) {
    const int kvB = it * 128;
    __syncthreads();  // sync0: prev-iter QK/PV reads of Ks/Vs complete before overwrite
#pragma unroll
    for (int r = 0; r < 4; ++r) {
      int c = r * 256 + tid;
      gload_lds16(Kg + (((size_t)bh * 2048 + kvB + (c & 127)) * 64 + (c >> 7) * 8), &Ks[c * 8]);
    }
#pragma unroll
    for (int r = 0; r < 4; ++r) {
      int c = r * 256 + tid;
      gload_lds16(Vtg + (((size_t)bh * 64 + (c & 63)) * 2048 + kvB + (c >> 6) * 8), &Vs[c * 8]);
    }
    __syncthreads();  // sync1: staging visible

    f32x4 s[8][2];
#pragma unroll
    for (int mt = 0; mt < 8; ++mt) {
      bf16x8 k0 = *(const bf16x8*)&Ks[((0 + quad) * 128 + mt * 16 + ln) * 8];
      bf16x8 k1 = *(const bf16x8*)&Ks[((4 + quad) * 128 + mt * 16 + ln) * 8];
#pragma unroll
      for (int qt = 0; qt < 2; ++qt) {
        f32x4 z = {0.f, 0.f, 0.f, 0.f};
        z = __builtin_amdgcn_mfma_f32_16x16x32_bf16(k0, qf[qt][0], z, 0, 0, 0);
        s[mt][qt] = __builtin_amdgcn_mfma_f32_16x16x32_bf16(k1, qf[qt][1], z, 0, 0, 0);
      }
    }

    unsigned ww[2][4];
    {
      uint4 m0 = *(const uint4*)(mrow[0] + it * 4);
      uint4 m1 = *(const uint4*)(mrow[1] + it * 4);
      ww[0][0] = m0.x; ww[0][1] = m0.y; ww[0][2] = m0.z; ww[0][3] = m0.w;
      ww[1][0] = m1.x; ww[1][1] = m1.y; ww[1][2] = m1.z; ww[1][3] = m1.w;
    }
    uint2 pk[8][2];
#pragma unroll
    for (int qt = 0; qt < 2; ++qt)
#pragma unroll
      for (int mt = 0; mt < 8; ++mt) {
        unsigned nib = (ww[qt][mt >> 1] >> ((mt & 1) * 16 + q4)) & 0xFu;
        float p0 = __builtin_amdgcn_exp2f((nib & 1u) ? s[mt][qt][0] : -1e30f);
        float p1 = __builtin_amdgcn_exp2f((nib & 2u) ? s[mt][qt][1] : -1e30f);
        float p2 = __builtin_amdgcn_exp2f((nib & 4u) ? s[mt][qt][2] : -1e30f);
        float p3 = __builtin_amdgcn_exp2f((nib & 8u) ? s[mt][qt][3] : -1e30f);
        pk[mt][qt].x = __builtin_amdgcn_perm(__float_as_uint(p1) + 0x8000u,
                                             __float_as_uint(p0) + 0x8000u, 0x07060302u);
        pk[mt][qt].y = __builtin_amdgcn_perm(__float_as_uint(p3) + 0x8000u,
                                             __float_as_uint(p2) + 0x8000u, 0x07060302u);
      }

    // P write -> PV read is intra-wave (own 32-row band): no barrier needed.
#pragma unroll
    for (int qt = 0; qt < 2; ++qt) {
      int qrow = wq + qt * 16 + ln;
#pragma unroll
      for (int mt = 0; mt < 8; ++mt)
        *(uint2*)&Ps[qrow * PSTR + mt * 16 + q4] = pk[mt][qt];
    }

#pragma unroll
    for (int kc2 = 0; kc2 < 4; ++kc2) {
      bf16x8 aP[2];
#pragma unroll
      for (int qt = 0; qt < 2; ++qt)
        aP[qt] = *(const bf16x8*)&Ps[(wq + qt * 16 + ln) * PSTR + kc2 * 32 + quad * 8];
#pragma unroll
      for (int nt = 0; nt < 4; ++nt) {
        bf16x8 bV = *(const bf16x8*)&Vs[((kc2 * 4 + quad) * 64 + nt * 16 + ln) * 8];
#pragma unroll
        for (int qt = 0; qt < 2; ++qt)
          oacc[qt][nt] = __builtin_amdgcn_mfma_f32_16x16x32_bf16(aP[qt], bV, oacc[qt][nt], 0, 0, 0);
      }
#pragma unroll
      for (int qt = 0; qt < 2; ++qt)
        lsum[qt] = __builtin_amdgcn_mfma_f32_16x16x32_bf16(aP[qt], vone, lsum[qt], 0, 0, 0);
    }
  }

  // epilogue: stage normalized O into Ps (own band only -> no pre-barrier needed)
#pragma unroll
  for (int qt = 0; qt < 2; ++qt)
#pragma unroll
    for (int r = 0; r < 4; ++r) {
      float il = 1.0f / lsum[qt][r];
      int q = wq + qt * 16 + q4 + r;
#pragma unroll
      for (int nt = 0; nt < 4; ++nt)
        Ps[q * 64 + nt * 16 + ln] = f2bf(oacc[qt][nt][r] * il);
    }
  __syncthreads();
#pragma unroll
  for (int r = 0; r < 4; ++r) {
    int c = r * 256 + tid;
    int q = c >> 3, ch = c & 7;
    *(uint4*)(ctx + ((size_t)(b * 2048 + qBase + q) * 1024 + h * 64 + ch * 8)) =
        *(const uint4*)&Ps[q * 64 + ch * 8];
  }
}

// ---------------- LayerNorm (fused +bo +residual) over 1024 features ----------------
__global__ __launch_bounds__(256) void ln_kernel(const float* __restrict__ x,
                                                 const float* __restrict__ resid,
                                                 const float* __restrict__ bo,
                                                 const float* __restrict__ gamma,
                                                 const float* __restrict__ beta,
                                                 float* __restrict__ out) {
  __shared__ float red[8];
  const int tid = threadIdx.x;
  const size_t row = blockIdx.x;
  float4 v = ((const float4*)(x + row * 1024))[tid];
  const float4 rr = ((const float4*)(resid + row * 1024))[tid];
  const float4 bb = ((const float4*)bo)[tid];
  v.x += rr.x + bb.x; v.y += rr.y + bb.y; v.z += rr.z + bb.z; v.w += rr.w + bb.w;
  float s1 = v.x + v.y + v.z + v.w;
  float s2 = v.x * v.x + v.y * v.y + v.z * v.z + v.w * v.w;
#pragma unroll
  for (int o = 32; o >= 1; o >>= 1) {
    s1 += __shfl_xor(s1, o);
    s2 += __shfl_xor(s2, o);
  }
  if ((tid & 63) == 0) { red[(tid >> 6) * 2] = s1; red[(tid >> 6) * 2 + 1] = s2; }
  __syncthreads();
  s1 = red[0] + red[2] + red[4] + red[6];
  s2 = red[1] + red[3] + red[5] + red[7];
  float mu = s1 * (1.f / 1024.f);
  float var = s2 * (1.f / 1024.f) - mu * mu;
  float inv = rsqrtf(var + 1e-5f);
  float4 g = ((const float4*)gamma)[tid];
  float4 be = ((const float4*)beta)[tid];
  float4 o;
  o.x = (v.x - mu) * inv * g.x + be.x;
  o.y = (v.y - mu) * inv * g.y + be.y;
  o.z = (v.z - mu) * inv * g.z + be.z;
  o.w = (v.w - mu) * inv * g.w + be.w;
  ((float4*)(out + row * 1024))[tid] = o;
}

extern "C" void kernel_launch(void* const* d_in, const int* in_sizes, int n_in,
                              void* d_out, int out_size, void* d_ws, size_t ws_size,
                              hipStream_t stream) {
  const float* query = (const float*)d_in[0];
  const float* key   = (const float*)d_in[1];
  const float* value = (const float*)d_in[2];
  const int*   mask  = (const int*)d_in[3];
  const float* w_q = (const float*)d_in[4];
  const float* b_q = (const float*)d_in[5];
  const float* w_k = (const float*)d_in[6];
  const float* b_k = (const float*)d_in[7];
  const float* w_v = (const float*)d_in[8];
  const float* b_v = (const float*)d_in[9];
  const float* w_o = (const float*)d_in[10];
  const float* b_o = (const float*)d_in[11];
  const float* ln_g = (const float*)d_in[12];
  const float* ln_b = (const float*)d_in[13];
  float* out = (float*)d_out;

  char* ws = (char*)d_ws;
  u16* Xq = (u16*)(ws + ((size_t)0 << 20));   // 8MB, reused as ctx after QKV GEMM
  u16* Xk = (u16*)(ws + ((size_t)8 << 20));   // 8MB  } reused as outpre (16MB f32)
  u16* Xv = (u16*)(ws + ((size_t)16 << 20));  // 8MB  }
  float* outpre = (float*)(ws + ((size_t)8 << 20));
  u16* Wq = (u16*)(ws + ((size_t)24 << 20));
  u16* Wk = (u16*)(ws + ((size_t)26 << 20));
  u16* Wv = (u16*)(ws + ((size_t)28 << 20));
  u16* Wo = (u16*)(ws + ((size_t)30 << 20));
  u16* Qd = (u16*)(ws + ((size_t)32 << 20));   // [b,h,s,64] bf16
  u16* Kd = (u16*)(ws + ((size_t)40 << 20));   // [b,h,s,64]
  u16* Vtd = (u16*)(ws + ((size_t)48 << 20));  // [b,h,64,s]
  unsigned long long* Mp = (unsigned long long*)(ws + ((size_t)56 << 20));  // 1MB
  u16* ctx = Xq;

  prep_kernel<<<20480, 256, 0, stream>>>(query, key, value, w_q, w_k, w_v, w_o, mask,
                                         Xq, Xk, Xv, Wq, Wk, Wv, Wo, Mp);
  gemm_kernel<<<dim3(32, 8, 3), 256, 0, stream>>>(Xq, Xk, Xv, Wq, Wk, Wv, Wo, ctx,
      b_q, b_k, b_v, Qd, Kd, Vtd, outpre, 0);
  attn_kernel<<<dim3(512), 256, 0, stream>>>(Qd, Kd, Vtd, (const unsigned*)Mp, ctx);
  gemm_kernel<<<dim3(32, 8, 1), 256, 0, stream>>>(Xq, Xk, Xv, Wq, Wk, Wv, Wo, ctx,
      b_q, b_k, b_v, Qd, Kd, Vtd, outpre, 3);
  ln_kernel<<<4096, 256, 0, stream>>>(outpre, query, b_o, ln_g, ln_b, out);
}

// Round 6
// 316.634 us; speedup vs baseline: 1.0638x; 1.0017x over previous
//
#include <hip/hip_runtime.h>

typedef unsigned short u16;
typedef __attribute__((ext_vector_type(8))) short bf16x8;
typedef __attribute__((ext_vector_type(4))) float f32x4;

#define LOG2E 1.4426950408889634f
#define QSCALE (LOG2E / 8.0f)   // fold 1/sqrt(64) and ln->log2 into Q projection
#define PSTR 72                 // attn P-half row stride: 36 words ≡ 4 mod 32 (same conflict profile as 136)

__device__ __forceinline__ u16 f2bf(float f) {
  union { float f; unsigned u; } v; v.f = f;
  unsigned r = v.u + 0x7fffu + ((v.u >> 16) & 1u);   // RNE
  return (u16)(r >> 16);
}

// async global->LDS, 16B per lane. LDS dest must be wave-uniform base + lane*16.
__device__ __forceinline__ void gload_lds16(const void* g, void* l) {
  __builtin_amdgcn_global_load_lds(
      (const __attribute__((address_space(1))) unsigned int*)(unsigned long long)g,
      (__attribute__((address_space(3))) unsigned int*)(unsigned int)(unsigned long long)l,
      16, 0, 0);
}

// ---------------- fused prep: 7x f32->bf16 convert + mask bit-pack ----------------
__global__ __launch_bounds__(256) void prep_kernel(
    const float* __restrict__ q, const float* __restrict__ k, const float* __restrict__ v,
    const float* __restrict__ wq, const float* __restrict__ wk, const float* __restrict__ wv,
    const float* __restrict__ wo, const int* __restrict__ mask,
    u16* __restrict__ Xq, u16* __restrict__ Xk, u16* __restrict__ Xv,
    u16* __restrict__ Wq, u16* __restrict__ Wk, u16* __restrict__ Wv, u16* __restrict__ Wo,
    unsigned long long* __restrict__ Mp) {
  const int bx = blockIdx.x;
  if (bx < 16384) {
    const float* src; u16* dst; float sc; int idx;
    if (bx < 12288) {
      int seg = bx >> 12;
      idx = (bx & 4095) * 256 + threadIdx.x;
      src = seg == 0 ? q : (seg == 1 ? k : v);
      dst = seg == 0 ? Xq : (seg == 1 ? Xk : Xv);
      sc = 1.f;
    } else {
      int t = bx - 12288, seg = t >> 10;
      idx = (t & 1023) * 256 + threadIdx.x;
      src = seg == 0 ? wq : (seg == 1 ? wk : (seg == 2 ? wv : wo));
      dst = seg == 0 ? Wq : (seg == 1 ? Wk : (seg == 2 ? Wv : Wo));
      sc = seg == 0 ? QSCALE : 1.f;
    }
    float4 x = ((const float4*)src)[idx];
    ushort4 o;
    o.x = f2bf(x.x * sc); o.y = f2bf(x.y * sc);
    o.z = f2bf(x.z * sc); o.w = f2bf(x.w * sc);
    ((ushort4*)dst)[idx] = o;
  } else {
    int gw = (((bx - 16384) * 256) + threadIdx.x) >> 6;   // [0,16384)
    int lane = threadIdx.x & 63;
    for (int w = gw; w < 131072; w += 16384) {
      int m = mask[(size_t)w * 64 + lane];
      unsigned long long b = __ballot(m != 0);
      if (lane == 0) Mp[w] = b;
    }
  }
}

// ---------------- fused GEMM: D[m][n] = sum_k A[m][k]*B[n][k]  (both k-contig, lda=ldb=1024)
// mode 0: A=Wq(f) B=Xq(s) -> Qd[b,h,s,d] bf16 (+bq*QSCALE)
// mode 1: A=Wk    B=Xk    -> Kd[b,h,s,d] bf16 (+bk)
// mode 2: A=Xv(s) B=Wv(f) -> Vtd[b,h,d,s] bf16 (+bv)
// mode 3: A=Wo(f) B=ctx(s)-> outp[s][f] f32 (raw matmul; bias+resid fused in LN)
__global__ __launch_bounds__(256, 3) void gemm_kernel(
    const u16* __restrict__ Xq, const u16* __restrict__ Xk, const u16* __restrict__ Xv,
    const u16* __restrict__ Wq, const u16* __restrict__ Wk, const u16* __restrict__ Wv,
    const u16* __restrict__ Wo, const u16* __restrict__ Ctx,
    const float* __restrict__ bq, const float* __restrict__ bk, const float* __restrict__ bv,
    u16* __restrict__ Qd, u16* __restrict__ Kd, u16* __restrict__ Vtd, float* __restrict__ outp,
    int mode_base) {
  __shared__ __align__(16) u16 SH[17408];  // main loop: As[4096]+Bs[4096]; epilogue: 34KB transpose tile
  u16* As = SH;
  u16* Bs = SH + 4096;
  const int mode = mode_base + blockIdx.z;
  const int tid = threadIdx.x;
  const int wid = tid >> 6, l = tid & 63, quad = l >> 4, ln = l & 15;
  const int wm = wid >> 1, wn = wid & 1;

  const u16 *A, *B; const float* bias;
  if (mode == 0)      { A = Wq; B = Xq;  bias = bq; }
  else if (mode == 1) { A = Wk; B = Xk;  bias = bk; }
  else if (mode == 2) { A = Xv; B = Wv;  bias = bv; }
  else                { A = Wo; B = Ctx; bias = bq; }
  int mBase, nBase;
  if (mode == 2) { mBase = blockIdx.x * 128; nBase = blockIdx.y * 128; }
  else           { mBase = blockIdx.y * 128; nBase = blockIdx.x * 128; }

  const u16* Ag = A + (size_t)mBase * 1024;
  const u16* Bg = B + (size_t)nBase * 1024;

  f32x4 acc[4][4] = {};

  for (int k0 = 0; k0 < 1024; k0 += 32) {
    if (k0) __syncthreads();
    {
      int i0 = tid, i1 = tid + 256;
      gload_lds16(Ag + (size_t)(i0 & 127) * 1024 + k0 + (i0 >> 7) * 8, &As[i0 * 8]);
      gload_lds16(Ag + (size_t)(i1 & 127) * 1024 + k0 + (i1 >> 7) * 8, &As[i1 * 8]);
      gload_lds16(Bg + (size_t)(i0 & 127) * 1024 + k0 + (i0 >> 7) * 8, &Bs[i0 * 8]);
      gload_lds16(Bg + (size_t)(i1 & 127) * 1024 + k0 + (i1 >> 7) * 8, &Bs[i1 * 8]);
    }
    __syncthreads();
    bf16x8 af[4], bf[4];
#pragma unroll
    for (int i = 0; i < 4; ++i)
      af[i] = *(const bf16x8*)&As[(quad * 128 + wm * 64 + i * 16 + ln) * 8];
#pragma unroll
    for (int j = 0; j < 4; ++j)
      bf[j] = *(const bf16x8*)&Bs[(quad * 128 + wn * 64 + j * 16 + ln) * 8];
#pragma unroll
    for (int i = 0; i < 4; ++i)
#pragma unroll
      for (int j = 0; j < 4; ++j)
        acc[i][j] = __builtin_amdgcn_mfma_f32_16x16x32_bf16(af[i], bf[j], acc[i][j], 0, 0, 0);
  }

  __syncthreads();  // all waves done with As/Bs before reusing SH for the transpose

  if (mode <= 1) {
    const float bscale = (mode == 0) ? QSCALE : 1.0f;
#pragma unroll
    for (int i = 0; i < 4; ++i) {
      int f0 = wm * 64 + i * 16 + quad * 4;
      float4 bb = *(const float4*)(bias + mBase + f0);
#pragma unroll
      for (int j = 0; j < 4; ++j) {
        int sl = wn * 64 + j * 16 + ln;
        f32x4 v = acc[i][j];
        ushort4 o;
        o.x = f2bf(v[0] + bb.x * bscale); o.y = f2bf(v[1] + bb.y * bscale);
        o.z = f2bf(v[2] + bb.z * bscale); o.w = f2bf(v[3] + bb.w * bscale);
        *(ushort4*)&SH[sl * 136 + f0] = o;
      }
    }
    __syncthreads();
    u16* dstQK = (mode == 0) ? Qd : Kd;
#pragma unroll
    for (int p = 0; p < 8; ++p) {
      int sl = p * 16 + (tid >> 4);
      int fl = (tid & 15) * 8;
      uint4 w = *(const uint4*)&SH[sl * 136 + fl];
      int s = nBase + sl, f = mBase + fl;
      int h = f >> 6, d = f & 63, b = s >> 11, sr = s & 2047;
      *(uint4*)(dstQK + (((size_t)(b * 16 + h) * 2048 + sr) * 64 + d)) = w;
    }
  } else if (mode == 2) {
#pragma unroll
    for (int j = 0; j < 4; ++j) {
      int fl = wn * 64 + j * 16 + ln;
      float bb = bias[nBase + fl];
#pragma unroll
      for (int i = 0; i < 4; ++i) {
        int s0 = wm * 64 + i * 16 + quad * 4;
        f32x4 v = acc[i][j];
        ushort4 o;
        o.x = f2bf(v[0] + bb); o.y = f2bf(v[1] + bb);
        o.z = f2bf(v[2] + bb); o.w = f2bf(v[3] + bb);
        *(ushort4*)&SH[fl * 136 + s0] = o;
      }
    }
    __syncthreads();
#pragma unroll
    for (int p = 0; p < 8; ++p) {
      int fl = p * 16 + (tid >> 4);
      int sl = (tid & 15) * 8;
      uint4 w = *(const uint4*)&SH[fl * 136 + sl];
      int f = nBase + fl, s = mBase + sl;
      int h = f >> 6, d = f & 63, b = s >> 11, sr = s & 2047;
      *(uint4*)(Vtd + (((size_t)(b * 16 + h) * 64 + d) * 2048 + sr)) = w;
    }
  } else {
    float* ES = (float*)SH;  // [64][stride 132] f32
#pragma unroll
    for (int h2 = 0; h2 < 2; ++h2) {
      if (h2) __syncthreads();
      if (wn == h2) {
#pragma unroll
        for (int i = 0; i < 4; ++i) {
          int f0 = wm * 64 + i * 16 + quad * 4;
#pragma unroll
          for (int j = 0; j < 4; ++j) {
            int sl = j * 16 + ln;
            f32x4 v = acc[i][j];
            float4 o; o.x = v[0]; o.y = v[1]; o.z = v[2]; o.w = v[3];
            *(float4*)&ES[sl * 132 + f0] = o;
          }
        }
      }
      __syncthreads();
#pragma unroll
      for (int p = 0; p < 8; ++p) {
        int sl = p * 8 + (tid >> 5);
        int fl = (tid & 31) * 4;
        float4 w = *(const float4*)&ES[sl * 132 + fl];
        int s = nBase + h2 * 64 + sl;
        *(float4*)(outp + (size_t)s * 1024 + mBase + fl) = w;
      }
    }
  }
}

// ---------------- flash attention (no-max exp2 softmax), 128-q tiles, XCD-swizzled ----------------
// 1-D grid of 512 blocks. bh = (L&7)+8*(L>>7): all 16 q-tiles of a head on one XCD -> K/V
// L2-resident (measured R5: FETCH 70->16 MB). P is processed in two kv-halves through a
// half-size LDS buffer: each wave touches only its own 32-q band (intra-wave, no barrier),
// so LDS = 16K(K)+16K(V)+18K(P) = 50KB -> 3 blocks/CU (was 2 at 66KB).
__global__ __launch_bounds__(256, 3) void attn_kernel(
    const u16* __restrict__ Qg, const u16* __restrict__ Kg, const u16* __restrict__ Vtg,
    const unsigned* __restrict__ Mp, u16* __restrict__ ctx) {
  __shared__ __align__(16) u16 Ks[8192];  // [dg 8][kv 128][8]
  __shared__ __align__(16) u16 Vs[8192];  // [kvg 16][d 64][8]
  __shared__ __align__(16) u16 Ps[9216];  // [q 128][PSTR=72] kv-half; reused as Os[128][64]
  const int tid = threadIdx.x;
  const int wid = tid >> 6, l = tid & 63, quad = l >> 4, ln = l & 15;
  const int q4 = quad * 4;
  const int L = blockIdx.x;
  const int bh = (L & 7) + 8 * (L >> 7);
  const int b = bh >> 4, h = bh & 15;
  const int qBase = ((L >> 3) & 15) * 128;
  const int wq = wid * 32;

  bf16x8 qf[2][2];  // B-operand fragments of Q (n=q=ln row, k=d contiguous)
#pragma unroll
  for (int qt = 0; qt < 2; ++qt)
#pragma unroll
    for (int kc = 0; kc < 2; ++kc)
      qf[qt][kc] = *(const bf16x8*)(Qg + (((size_t)bh * 2048 + qBase + wq + qt * 16 + ln) * 64 +
                                          kc * 32 + quad * 8));

  f32x4 oacc[2][4] = {};
  f32x4 lsum[2] = {};
  const bf16x8 vone = {(short)0x3F80, (short)0x3F80, (short)0x3F80, (short)0x3F80,
                       (short)0x3F80, (short)0x3F80, (short)0x3F80, (short)0x3F80};

  const unsigned* mrow[2];  // 64 u32 mask words per q row
  mrow[0] = Mp + ((size_t)b * 2048 + qBase + wq + ln) * 64;
  mrow[1] = mrow[0] + 16 * 64;

  for (int it = 0; it < 16; ++it) {
    const int kvB = it * 128;
    __syncthreads();  // sync0: prev-iter QK/PV reads of Ks/Vs complete before overwrite
#pragma unroll
    for (int r = 0; r < 4; ++r) {
      int c = r * 256 + tid;
      gload_lds16(Kg + (((size_t)bh * 2048 + kvB + (c & 127)) * 64 + (c >> 7) * 8), &Ks[c * 8]);
    }
#pragma unroll
    for (int r = 0; r < 4; ++r) {
      int c = r * 256 + tid;
      gload_lds16(Vtg + (((size_t)bh * 64 + (c & 63)) * 2048 + kvB + (c >> 6) * 8), &Vs[c * 8]);
    }
    __syncthreads();  // sync1: staging visible

    unsigned ww[2][4];
    {
      uint4 m0 = *(const uint4*)(mrow[0] + it * 4);
      uint4 m1 = *(const uint4*)(mrow[1] + it * 4);
      ww[0][0] = m0.x; ww[0][1] = m0.y; ww[0][2] = m0.z; ww[0][3] = m0.w;
      ww[1][0] = m1.x; ww[1][1] = m1.y; ww[1][2] = m1.z; ww[1][3] = m1.w;
    }

#pragma unroll
    for (int hf = 0; hf < 2; ++hf) {  // kv half: [hf*64, hf*64+64)
      f32x4 s[4][2];
#pragma unroll
      for (int m2 = 0; m2 < 4; ++m2) {
        int mt = hf * 4 + m2;
        bf16x8 k0 = *(const bf16x8*)&Ks[((0 + quad) * 128 + mt * 16 + ln) * 8];
        bf16x8 k1 = *(const bf16x8*)&Ks[((4 + quad) * 128 + mt * 16 + ln) * 8];
#pragma unroll
        for (int qt = 0; qt < 2; ++qt) {
          f32x4 z = {0.f, 0.f, 0.f, 0.f};
          z = __builtin_amdgcn_mfma_f32_16x16x32_bf16(k0, qf[qt][0], z, 0, 0, 0);
          s[m2][qt] = __builtin_amdgcn_mfma_f32_16x16x32_bf16(k1, qf[qt][1], z, 0, 0, 0);
        }
      }

      uint2 pk[4][2];
#pragma unroll
      for (int qt = 0; qt < 2; ++qt)
#pragma unroll
        for (int m2 = 0; m2 < 4; ++m2) {
          int mt = hf * 4 + m2;
          unsigned nib = (ww[qt][mt >> 1] >> ((mt & 1) * 16 + q4)) & 0xFu;
          float p0 = __builtin_amdgcn_exp2f((nib & 1u) ? s[m2][qt][0] : -1e30f);
          float p1 = __builtin_amdgcn_exp2f((nib & 2u) ? s[m2][qt][1] : -1e30f);
          float p2 = __builtin_amdgcn_exp2f((nib & 4u) ? s[m2][qt][2] : -1e30f);
          float p3 = __builtin_amdgcn_exp2f((nib & 8u) ? s[m2][qt][3] : -1e30f);
          pk[m2][qt].x = __builtin_amdgcn_perm(__float_as_uint(p1) + 0x8000u,
                                               __float_as_uint(p0) + 0x8000u, 0x07060302u);
          pk[m2][qt].y = __builtin_amdgcn_perm(__float_as_uint(p3) + 0x8000u,
                                               __float_as_uint(p2) + 0x8000u, 0x07060302u);
        }

      // P write -> PV read is intra-wave (own 32-row band): no barrier needed.
#pragma unroll
      for (int qt = 0; qt < 2; ++qt) {
        int qrow = wq + qt * 16 + ln;
#pragma unroll
        for (int m2 = 0; m2 < 4; ++m2)
          *(uint2*)&Ps[qrow * PSTR + m2 * 16 + q4] = pk[m2][qt];
      }

#pragma unroll
      for (int k2 = 0; k2 < 2; ++k2) {  // kv 32-chunks within the half
        int kc2 = hf * 2 + k2;
        bf16x8 aP[2];
#pragma unroll
        for (int qt = 0; qt < 2; ++qt)
          aP[qt] = *(const bf16x8*)&Ps[(wq + qt * 16 + ln) * PSTR + k2 * 32 + quad * 8];
#pragma unroll
        for (int nt = 0; nt < 4; ++nt) {
          bf16x8 bV = *(const bf16x8*)&Vs[((kc2 * 4 + quad) * 64 + nt * 16 + ln) * 8];
#pragma unroll
          for (int qt = 0; qt < 2; ++qt)
            oacc[qt][nt] = __builtin_amdgcn_mfma_f32_16x16x32_bf16(aP[qt], bV, oacc[qt][nt], 0, 0, 0);
        }
#pragma unroll
        for (int qt = 0; qt < 2; ++qt)
          lsum[qt] = __builtin_amdgcn_mfma_f32_16x16x32_bf16(aP[qt], vone, lsum[qt], 0, 0, 0);
      }
    }
  }

  // epilogue: stage normalized O into Ps (own band only -> no pre-barrier needed)
  __syncthreads();  // all waves done with Ps as P-halves
#pragma unroll
  for (int qt = 0; qt < 2; ++qt)
#pragma unroll
    for (int r = 0; r < 4; ++r) {
      float il = 1.0f / lsum[qt][r];
      int q = wq + qt * 16 + q4 + r;
#pragma unroll
      for (int nt = 0; nt < 4; ++nt)
        Ps[q * 64 + nt * 16 + ln] = f2bf(oacc[qt][nt][r] * il);
    }
  __syncthreads();
#pragma unroll
  for (int r = 0; r < 4; ++r) {
    int c = r * 256 + tid;
    int q = c >> 3, ch = c & 7;
    *(uint4*)(ctx + ((size_t)(b * 2048 + qBase + q) * 1024 + h * 64 + ch * 8)) =
        *(const uint4*)&Ps[q * 64 + ch * 8];
  }
}

// ---------------- LayerNorm (fused +bo +residual) over 1024 features ----------------
__global__ __launch_bounds__(256) void ln_kernel(const float* __restrict__ x,
                                                 const float* __restrict__ resid,
                                                 const float* __restrict__ bo,
                                                 const float* __restrict__ gamma,
                                                 const float* __restrict__ beta,
                                                 float* __restrict__ out) {
  __shared__ float red[8];
  const int tid = threadIdx.x;
  const size_t row = blockIdx.x;
  float4 v = ((const float4*)(x + row * 1024))[tid];
  const float4 rr = ((const float4*)(resid + row * 1024))[tid];
  const float4 bb = ((const float4*)bo)[tid];
  v.x += rr.x + bb.x; v.y += rr.y + bb.y; v.z += rr.z + bb.z; v.w += rr.w + bb.w;
  float s1 = v.x + v.y + v.z + v.w;
  float s2 = v.x * v.x + v.y * v.y + v.z * v.z + v.w * v.w;
#pragma unroll
  for (int o = 32; o >= 1; o >>= 1) {
    s1 += __shfl_xor(s1, o);
    s2 += __shfl_xor(s2, o);
  }
  if ((tid & 63) == 0) { red[(tid >> 6) * 2] = s1; red[(tid >> 6) * 2 + 1] = s2; }
  __syncthreads();
  s1 = red[0] + red[2] + red[4] + red[6];
  s2 = red[1] + red[3] + red[5] + red[7];
  float mu = s1 * (1.f / 1024.f);
  float var = s2 * (1.f / 1024.f) - mu * mu;
  float inv = rsqrtf(var + 1e-5f);
  float4 g = ((const float4*)gamma)[tid];
  float4 be = ((const float4*)beta)[tid];
  float4 o;
  o.x = (v.x - mu) * inv * g.x + be.x;
  o.y = (v.y - mu) * inv * g.y + be.y;
  o.z = (v.z - mu) * inv * g.z + be.z;
  o.w = (v.w - mu) * inv * g.w + be.w;
  ((float4*)(out + row * 1024))[tid] = o;
}

extern "C" void kernel_launch(void* const* d_in, const int* in_sizes, int n_in,
                              void* d_out, int out_size, void* d_ws, size_t ws_size,
                              hipStream_t stream) {
  const float* query = (const float*)d_in[0];
  const float* key   = (const float*)d_in[1];
  const float* value = (const float*)d_in[2];
  const int*   mask  = (const int*)d_in[3];
  const float* w_q = (const float*)d_in[4];
  const float* b_q = (const float*)d_in[5];
  const float* w_k = (const float*)d_in[6];
  const float* b_k = (const float*)d_in[7];
  const float* w_v = (const float*)d_in[8];
  const float* b_v = (const float*)d_in[9];
  const float* w_o = (const float*)d_in[10];
  const float* b_o = (const float*)d_in[11];
  const float* ln_g = (const float*)d_in[12];
  const float* ln_b = (const float*)d_in[13];
  float* out = (float*)d_out;

  char* ws = (char*)d_ws;
  u16* Xq = (u16*)(ws + ((size_t)0 << 20));   // 8MB, reused as ctx after QKV GEMM
  u16* Xk = (u16*)(ws + ((size_t)8 << 20));   // 8MB  } reused as outpre (16MB f32)
  u16* Xv = (u16*)(ws + ((size_t)16 << 20));  // 8MB  }
  float* outpre = (float*)(ws + ((size_t)8 << 20));
  u16* Wq = (u16*)(ws + ((size_t)24 << 20));
  u16* Wk = (u16*)(ws + ((size_t)26 << 20));
  u16* Wv = (u16*)(ws + ((size_t)28 << 20));
  u16* Wo = (u16*)(ws + ((size_t)30 << 20));
  u16* Qd = (u16*)(ws + ((size_t)32 << 20));   // [b,h,s,64] bf16
  u16* Kd = (u16*)(ws + ((size_t)40 << 20));   // [b,h,s,64]
  u16* Vtd = (u16*)(ws + ((size_t)48 << 20));  // [b,h,64,s]
  unsigned long long* Mp = (unsigned long long*)(ws + ((size_t)56 << 20));  // 1MB
  u16* ctx = Xq;

  prep_kernel<<<20480, 256, 0, stream>>>(query, key, value, w_q, w_k, w_v, w_o, mask,
                                         Xq, Xk, Xv, Wq, Wk, Wv, Wo, Mp);
  gemm_kernel<<<dim3(32, 8, 3), 256, 0, stream>>>(Xq, Xk, Xv, Wq, Wk, Wv, Wo, ctx,
      b_q, b_k, b_v, Qd, Kd, Vtd, outpre, 0);
  attn_kernel<<<dim3(512), 256, 0, stream>>>(Qd, Kd, Vtd, (const unsigned*)Mp, ctx);
  gemm_kernel<<<dim3(32, 8, 1), 256, 0, stream>>>(Xq, Xk, Xv, Wq, Wk, Wv, Wo, ctx,
      b_q, b_k, b_v, Qd, Kd, Vtd, outpre, 3);
  ln_kernel<<<4096, 256, 0, stream>>>(outpre, query, b_o, ln_g, ln_b, out);
}